// Round 4
// baseline (148.934 us; speedup 1.0000x reference)
//
#include <hip/hip_runtime.h>
#include <math.h>

#define NSWEEP 6
static constexpr int Bn = 32768;

// ws layout (floats)
#define WS_COEF  0        // [64][28] : per n {w, qc[3], cb[24]}  (cb idx = k*3+j)
#define WS_G     1792     // [8][8]
#define WS_g     1856     // [8]
#define WS_BW    1864     // [24]  b_w[k*3+m]
#define WS_Q00   1888
#define WS_WSUM  1889
#define WS_BATCH 1920     // [130][Bn] : 0..54 Qsym(upper), 55..126 FG[k*9+e], 127..129 y_w
#define WS_LMIN  (1920 + 130*Bn)   // [Bn]

__host__ __device__ constexpr int tidx(int i, int j) { return i*10 - i*(i+1)/2 + j; } // i<=j (upper packed)
__host__ __device__ constexpr int tmm(int i, int j)  { return (i<j) ? tidx(i,j) : tidx(j,i); }
__host__ __device__ constexpr int lidx(int i, int j) { return i*(i+1)/2 + j; }        // i>=j (lower packed)

// ---------------- K1: precompute (1 block, 64 threads) ----------------
__global__ void k_pre(const float* __restrict__ bb, const float* __restrict__ w,
                      const float* __restrict__ lam, float* __restrict__ ws)
{
  __shared__ float s_w[64], s_sw[64], s_bw[24], s_barb[64][24];
  __shared__ float s_BtB[64];
  __shared__ float s_G[64], s_g[8], s_wsum;
  const int t = threadIdx.x;
  s_w[t]  = w[t];
  s_sw[t] = sqrtf(fmaxf(s_w[t], 0.0f));
  __syncthreads();
  if (t == 0) { float a = 0; for (int n = 0; n < 64; n++) a += s_w[n]; s_wsum = a; }
  __syncthreads();
  const float wsum = s_wsum;
  if (t < 24) {
    float a = 0;
    for (int n = 0; n < 64; n++) a += bb[t*64 + n] * s_w[n];
    s_bw[t] = a / wsum;
  }
  __syncthreads();
  for (int km = 0; km < 24; ++km)
    s_barb[t][km] = s_sw[t] * (bb[km*64 + t] - s_bw[km]);
  __syncthreads();
  {
    int k = t >> 3, k2 = t & 7;
    float a = 0;
    for (int n = 0; n < 64; n++)
      for (int j = 0; j < 3; j++)
        a += s_barb[n][k*3 + j] * s_barb[n][k2*3 + j];
    s_BtB[t] = a;
  }
  __syncthreads();
  if (t == 0) {
    const float lv = lam[0];
    float A[8][8], Iv[8][8];
#pragma unroll
    for (int i = 0; i < 8; i++)
#pragma unroll
      for (int j = 0; j < 8; j++) {
        A[i][j]  = 2.0f * (s_BtB[i*8 + j] + ((i == j) ? lv : 0.0f));
        Iv[i][j] = (i == j) ? 1.0f : 0.0f;
      }
#pragma unroll
    for (int k = 0; k < 8; k++) {
      float piv = 1.0f / A[k][k];
#pragma unroll
      for (int j = 0; j < 8; j++) { A[k][j] *= piv; Iv[k][j] *= piv; }
#pragma unroll
      for (int i = 0; i < 8; i++) {
        if (i == k) continue;
        float f = A[i][k];
#pragma unroll
        for (int j = 0; j < 8; j++) { A[i][j] -= f * A[k][j]; Iv[i][j] -= f * Iv[k][j]; }
      }
    }
    float u[8]; float s = 0;
#pragma unroll
    for (int i = 0; i < 8; i++) {
      float a = 0;
#pragma unroll
      for (int j = 0; j < 8; j++) a += Iv[i][j];
      u[i] = a; s += a;
    }
#pragma unroll
    for (int i = 0; i < 8; i++) s_g[i] = u[i] / s;
    float q00 = 0.0f;
#pragma unroll
    for (int i = 0; i < 8; i++)
#pragma unroll
      for (int j = 0; j < 8; j++) {
        s_G[i*8 + j] = Iv[i][j] - u[i]*u[j]/s;
        q00 += s_g[i] * (s_BtB[i*8 + j] + ((i == j) ? lv : 0.0f)) * s_g[j];
      }
    ws[WS_Q00]  = q00;
    ws[WS_WSUM] = wsum;
  }
  __syncthreads();
  if (t < 8)  ws[WS_g + t]  = s_g[t];
  if (t < 24) ws[WS_BW + t] = s_bw[t];
  ws[WS_G + t] = s_G[t];
  {
    float* c = ws + WS_COEF + t*28;
    c[0] = s_w[t];
    float qc[3] = {0, 0, 0};
#pragma unroll
    for (int km = 0; km < 24; km++) {
      float cb = s_sw[t] * s_barb[t][km];
      c[4 + km] = cb;
      qc[km % 3] += s_g[km / 3] * cb;
    }
    c[1] = qc[0]; c[2] = qc[1]; c[3] = qc[2];
  }
}

// ---------------- K2: per-batch Q build ----------------
__global__ __launch_bounds__(256) void k_build(const float* __restrict__ y, float* ws)
{
  const int b = blockIdx.x * 256 + threadIdx.x;
  const float* yb = y + (size_t)b * 192;
  const float* coef = ws + WS_COEF;
  float F[24][3];
  float qt[3][3];
  float gw[6];
  float ywa[3] = {0, 0, 0};
#pragma unroll
  for (int i = 0; i < 24; i++) { F[i][0] = 0; F[i][1] = 0; F[i][2] = 0; }
#pragma unroll
  for (int i = 0; i < 9; i++) qt[i/3][i%3] = 0;
#pragma unroll
  for (int i = 0; i < 6; i++) gw[i] = 0;

  for (int n4 = 0; n4 < 16; n4++) {
    float4 v0 = reinterpret_cast<const float4*>(yb)[n4];
    float4 v1 = reinterpret_cast<const float4*>(yb + 64)[n4];
    float4 v2 = reinterpret_cast<const float4*>(yb + 128)[n4];
    float a0[4] = {v0.x, v0.y, v0.z, v0.w};
    float a1[4] = {v1.x, v1.y, v1.z, v1.w};
    float a2[4] = {v2.x, v2.y, v2.z, v2.w};
#pragma unroll
    for (int l = 0; l < 4; l++) {
      const int n = 4*n4 + l;
      const float* c = coef + n*28;
      float ym0 = a0[l], ym1 = a1[l], ym2 = a2[l];
      float wn  = c[0];
      float wy0 = wn*ym0, wy1 = wn*ym1, wy2 = wn*ym2;
      ywa[0] += wy0; ywa[1] += wy1; ywa[2] += wy2;
      gw[0] += wy0*ym0; gw[1] += wy0*ym1; gw[2] += wy0*ym2;
      gw[3] += wy1*ym1; gw[4] += wy1*ym2; gw[5] += wy2*ym2;
#pragma unroll
      for (int j = 0; j < 3; j++) {
        float qcv = c[1 + j];
        qt[j][0] += qcv*ym0; qt[j][1] += qcv*ym1; qt[j][2] += qcv*ym2;
      }
#pragma unroll
      for (int kj = 0; kj < 24; kj++) {
        float cb = c[4 + kj];
        F[kj][0] += cb*ym0; F[kj][1] += cb*ym1; F[kj][2] += cb*ym2;
      }
    }
  }
  const float wsum = ws[WS_WSUM];
  const float q00  = ws[WS_Q00];
  const float iws  = 1.0f / wsum;
  float yw[3] = {ywa[0]*iws, ywa[1]*iws, ywa[2]*iws};
  float Gram[3][3];
  Gram[0][0] = gw[0] - ywa[0]*ywa[0]*iws;
  Gram[0][1] = Gram[1][0] = gw[1] - ywa[0]*ywa[1]*iws;
  Gram[0][2] = Gram[2][0] = gw[2] - ywa[0]*ywa[2]*iws;
  Gram[1][1] = gw[3] - ywa[1]*ywa[1]*iws;
  Gram[1][2] = Gram[2][1] = gw[4] - ywa[1]*ywa[2]*iws;
  Gram[2][2] = gw[5] - ywa[2]*ywa[2]*iws;

  float Gm[64];
#pragma unroll
  for (int i = 0; i < 64; i++) Gm[i] = ws[WS_G + i];
  float FG[8][9];
#pragma unroll
  for (int k2 = 0; k2 < 8; k2++)
#pragma unroll
    for (int e = 0; e < 9; e++) {
      const int j = e / 3, m = e % 3;
      float a = 0;
#pragma unroll
      for (int k = 0; k < 8; k++) a += Gm[k*8 + k2] * F[k*3 + j][m];
      FG[k2][e] = a;
    }
  float q[55];
  q[tidx(0,0)] = q00;
#pragma unroll
  for (int e = 0; e < 9; e++) q[tidx(0, 1 + e)] = -qt[e/3][e%3];
#pragma unroll
  for (int e = 0; e < 9; e++)
#pragma unroll
    for (int f = e; f < 9; f++) {
      const int j = e/3, m = e%3, j2 = f/3, m2 = f%3;
      float a = 0;
#pragma unroll
      for (int k = 0; k < 8; k++) a += FG[k][e] * F[k*3 + j2][m2];
      q[tidx(1 + e, 1 + f)] = -2.0f*a + ((j == j2) ? Gram[m][m2] : 0.0f);
    }
  float* wb = ws + WS_BATCH;
#pragma unroll
  for (int i = 0; i < 55; i++) wb[(size_t)i*Bn + b] = q[i];
#pragma unroll
  for (int k = 0; k < 8; k++)
#pragma unroll
    for (int e = 0; e < 9; e++)
      wb[(size_t)(55 + k*9 + e)*Bn + b] = FG[k][e];
#pragma unroll
  for (int m = 0; m < 3; m++) wb[(size_t)(127 + m)*Bn + b] = yw[m];
}

// ---------------- K3a: eigenvalue-only cyclic Jacobi -> lmin ----------------
__global__ __launch_bounds__(64, 1) void k_jac(const float* __restrict__ ws,
                                               float* __restrict__ ws_out)
{
  const int b = blockIdx.x * 64 + threadIdx.x;
  const float* wb = ws + WS_BATCH;
  float A[55];
#pragma unroll
  for (int i = 0; i < 55; i++) A[i] = wb[(size_t)i*Bn + b];

  for (int sweep = 0; sweep < NSWEEP; ++sweep) {
#pragma unroll
    for (int p = 0; p < 10; p++) {
#pragma unroll
      for (int q = p + 1; q < 10; q++) {
        float apq = A[tidx(p,q)];
        float app = A[tidx(p,p)];
        float aqq = A[tidx(q,q)];
        float theta = 0.5f * (aqq - app) * __builtin_amdgcn_rcpf(apq);
        float tt = __builtin_amdgcn_rcpf(fabsf(theta) +
                     __builtin_amdgcn_sqrtf(theta*theta + 1.0f));
        tt = (theta < 0.0f) ? -tt : tt;
        tt = (fabsf(apq) <= 1e-30f) ? 0.0f : tt;     // round-2 guard
        float cth = __builtin_amdgcn_rsqf(tt*tt + 1.0f);
        float sth = tt * cth;
        A[tidx(p,p)] = app - tt*apq;
        A[tidx(q,q)] = aqq + tt*apq;
        A[tidx(p,q)] = 0.0f;
#pragma unroll
        for (int i = 0; i < 10; i++) {
          if (i == p || i == q) continue;
          float aip = A[tmm(i,p)];
          float aiq = A[tmm(i,q)];
          A[tmm(i,p)] = cth*aip - sth*aiq;
          A[tmm(i,q)] = sth*aip + cth*aiq;
        }
      }
    }
  }
  float lmin = A[tidx(0,0)];
#pragma unroll
  for (int j = 1; j < 10; j++) lmin = fminf(lmin, A[tidx(j,j)]);
  ws_out[WS_LMIN + b] = lmin;
}

// ---------------- K3b: Cholesky inverse iteration + outputs ----------------
__global__ __launch_bounds__(64, 1) void k_vec(const float* __restrict__ ws,
                                               float* __restrict__ out)
{
  const int b = blockIdx.x * 64 + threadIdx.x;
  const float* wb = ws + WS_BATCH;
  const float lmin = ws[WS_LMIN + b];

  float M[55];                 // packed lower
  float id[10];
#pragma unroll
  for (int i = 0; i < 10; i++)
#pragma unroll
    for (int j = 0; j <= i; j++)
      M[lidx(i,j)] = wb[(size_t)tidx(j,i)*Bn + b];
  float tr = 0.0f;
#pragma unroll
  for (int i = 0; i < 10; i++) tr += M[lidx(i,i)];

  const float delta = 1e-5f * fabsf(tr) + 1e-30f;   // round-2 margin
  const float sigma = lmin - delta;
#pragma unroll
  for (int i = 0; i < 10; i++) M[lidx(i,i)] -= sigma;

#pragma unroll
  for (int j = 0; j < 10; j++) {
    float d = M[lidx(j,j)];
#pragma unroll
    for (int t2 = 0; t2 < j; t2++) d -= M[lidx(j,t2)] * M[lidx(j,t2)];
    d = fmaxf(d, 1e-30f);                            // round-2 floor
    float is = __builtin_amdgcn_rsqf(d);
    id[j] = is;
#pragma unroll
    for (int i = j + 1; i < 10; i++) {
      float a = M[lidx(i,j)];
#pragma unroll
      for (int t2 = 0; t2 < j; t2++) a -= M[lidx(i,t2)] * M[lidx(j,t2)];
      M[lidx(i,j)] = a * is;
    }
  }

  float x[10];
#pragma unroll
  for (int i = 0; i < 10; i++) x[i] = 1.0f;

#pragma unroll
  for (int it = 0; it < 3; ++it) {
#pragma unroll
    for (int i = 0; i < 10; i++) {
      float a = x[i];
#pragma unroll
      for (int j = 0; j < i; j++) a -= M[lidx(i,j)] * x[j];
      x[i] = a * id[i];
    }
#pragma unroll
    for (int i = 9; i >= 0; i--) {
      float a = x[i];
#pragma unroll
      for (int j = i + 1; j < 10; j++) a -= M[lidx(j,i)] * x[j];
      x[i] = a * id[i];
    }
    float s2 = 0;
#pragma unroll
    for (int i = 0; i < 10; i++) s2 += x[i]*x[i];
    float sc = __builtin_amdgcn_rsqf(s2 + 1e-38f);
#pragma unroll
    for (int i = 0; i < 10; i++) x[i] *= sc;
  }

  const float inv0 = __builtin_amdgcn_rcpf(x[0]);
  float R[3][3];
#pragma unroll
  for (int r = 0; r < 3; r++)
#pragma unroll
    for (int cc = 0; cc < 3; cc++)
      R[r][cc] = x[1 + 3*cc + r] * inv0;
  float cvec[8];
#pragma unroll
  for (int k = 0; k < 8; k++) {
    float a = 0;
#pragma unroll
    for (int e = 0; e < 9; e++) a += x[1 + e] * wb[(size_t)(55 + k*9 + e)*Bn + b];
    cvec[k] = 2.0f * inv0 * a + ws[WS_g + k];
  }
  float um[3] = {0, 0, 0};
#pragma unroll
  for (int k = 0; k < 8; k++) {
    float ck = cvec[k];
    um[0] += ws[WS_BW + k*3 + 0] * ck;
    um[1] += ws[WS_BW + k*3 + 1] * ck;
    um[2] += ws[WS_BW + k*3 + 2] * ck;
  }
#pragma unroll
  for (int r = 0; r < 3; r++)
#pragma unroll
    for (int cc = 0; cc < 3; cc++)
      out[(size_t)b*9 + r*3 + cc] = R[r][cc];
#pragma unroll
  for (int r = 0; r < 3; r++) {
    float yw = wb[(size_t)(127 + r)*Bn + b];
    out[(size_t)9*Bn + b*3 + r] = yw - (R[r][0]*um[0] + R[r][1]*um[1] + R[r][2]*um[2]);
  }
#pragma unroll
  for (int k = 0; k < 8; k++)
    out[(size_t)12*Bn + b*8 + k] = cvec[k];
}

extern "C" void kernel_launch(void* const* d_in, const int* in_sizes, int n_in,
                              void* d_out, int out_size, void* d_ws, size_t ws_size,
                              hipStream_t stream) {
  const float* y   = (const float*)d_in[0];
  const float* bb  = (const float*)d_in[1];
  const float* w   = (const float*)d_in[2];
  const float* lam = (const float*)d_in[3];
  float* ws  = (float*)d_ws;
  float* out = (float*)d_out;
  k_pre  <<<1,        64, 0, stream>>>(bb, w, lam, ws);
  k_build<<<Bn/256,  256, 0, stream>>>(y, ws);
  k_jac  <<<Bn/64,    64, 0, stream>>>(ws, ws);
  k_vec  <<<Bn/64,    64, 0, stream>>>(ws, out);
}

// Round 5
// 90.702 us; speedup vs baseline: 1.6420x; 1.6420x over previous
//
#include <hip/hip_runtime.h>
#include <math.h>

#define NSWEEP 6
static constexpr int Bn = 32768;

// ws layout (floats)
#define WS_COEF  0        // [64][28] : per n {w, qc[3], cb[24]}  (cb idx = k*3+j)
#define WS_G     1792     // [8][8]
#define WS_g     1856     // [8]
#define WS_BW    1864     // [24]  b_w[k*3+m]
#define WS_Q00   1888
#define WS_WSUM  1889
#define WS_BATCH 1920     // [130][Bn] : 0..54 Qsym(upper), 55..126 FG[k*9+e], 127..129 y_w
#define WS_LMIN  (1920 + 130*Bn)   // [Bn]

__host__ __device__ constexpr int tidx(int i, int j) { return i*10 - i*(i+1)/2 + j; } // i<=j (upper packed)
__host__ __device__ constexpr int tmm(int i, int j)  { return (i<j) ? tidx(i,j) : tidx(j,i); }
__host__ __device__ constexpr int lidx(int i, int j) { return i*(i+1)/2 + j; }        // i>=j (lower packed)

// ---- 55 named scalars: guaranteed SROA-promotable (no dynamic index possible) ----
#define ALL55(F) \
  F(0) F(1) F(2) F(3) F(4) F(5) F(6) F(7) F(8) F(9) \
  F(10) F(11) F(12) F(13) F(14) F(15) F(16) F(17) F(18) F(19) \
  F(20) F(21) F(22) F(23) F(24) F(25) F(26) F(27) F(28) F(29) \
  F(30) F(31) F(32) F(33) F(34) F(35) F(36) F(37) F(38) F(39) \
  F(40) F(41) F(42) F(43) F(44) F(45) F(46) F(47) F(48) F(49) \
  F(50) F(51) F(52) F(53) F(54)

#define DECLF(N) float v##N;
struct S10 { ALL55(DECLF) };

template<int I> __device__ __forceinline__ float& at(S10& s);
#define DEFAT(N) template<> __device__ __forceinline__ float& at<N>(S10& s) { return s.v##N; }
ALL55(DEFAT)

template<int I>
__device__ __forceinline__ void loadA(S10& A, const float* __restrict__ wb, int b) {
  if constexpr (I < 55) {
    at<I>(A) = wb[(size_t)I*Bn + b];
    loadA<I + 1>(A, wb, b);
  }
}

template<int P, int Q, int I>
__device__ __forceinline__ void rotrow(S10& A, float cth, float sth) {
  if constexpr (I < 10) {
    if constexpr (I != P && I != Q) {
      float aip = at<tmm(I,P)>(A);
      float aiq = at<tmm(I,Q)>(A);
      at<tmm(I,P)>(A) = cth*aip - sth*aiq;
      at<tmm(I,Q)>(A) = sth*aip + cth*aiq;
    }
    rotrow<P, Q, I + 1>(A, cth, sth);
  }
}

template<int P, int Q>
__device__ __forceinline__ void rot(S10& A) {
  float apq = at<tidx(P,Q)>(A);
  float app = at<tidx(P,P)>(A);
  float aqq = at<tidx(Q,Q)>(A);
  float theta = 0.5f * (aqq - app) * __builtin_amdgcn_rcpf(apq);
  float tt = __builtin_amdgcn_rcpf(fabsf(theta) +
               __builtin_amdgcn_sqrtf(theta*theta + 1.0f));
  tt = (theta < 0.0f) ? -tt : tt;
  tt = (fabsf(apq) <= 1e-30f) ? 0.0f : tt;      // round-2 guard
  float cth = __builtin_amdgcn_rsqf(tt*tt + 1.0f);
  float sth = tt * cth;
  at<tidx(P,P)>(A) = app - tt*apq;
  at<tidx(Q,Q)>(A) = aqq + tt*apq;
  at<tidx(P,Q)>(A) = 0.0f;
  rotrow<P, Q, 0>(A, cth, sth);
}

template<int P, int Q>
__device__ __forceinline__ void sweepFrom(S10& A) {
  if constexpr (P < 10) {
    if constexpr (Q < 10) {
      rot<P, Q>(A);
      sweepFrom<P, Q + 1>(A);
    } else {
      sweepFrom<P + 1, P + 2>(A);
    }
  }
}

template<int J>
__device__ __forceinline__ void dmin(S10& A, float& m) {
  if constexpr (J < 10) {
    m = fminf(m, at<tidx(J,J)>(A));
    dmin<J + 1>(A, m);
  }
}

// ---------------- K1: precompute (1 block, 64 threads) ----------------
__global__ void k_pre(const float* __restrict__ bb, const float* __restrict__ w,
                      const float* __restrict__ lam, float* __restrict__ ws)
{
  __shared__ float s_w[64], s_sw[64], s_bw[24], s_barb[64][24];
  __shared__ float s_BtB[64];
  __shared__ float s_G[64], s_g[8], s_wsum;
  const int t = threadIdx.x;
  s_w[t]  = w[t];
  s_sw[t] = sqrtf(fmaxf(s_w[t], 0.0f));
  __syncthreads();
  if (t == 0) { float a = 0; for (int n = 0; n < 64; n++) a += s_w[n]; s_wsum = a; }
  __syncthreads();
  const float wsum = s_wsum;
  if (t < 24) {
    float a = 0;
    for (int n = 0; n < 64; n++) a += bb[t*64 + n] * s_w[n];
    s_bw[t] = a / wsum;
  }
  __syncthreads();
  for (int km = 0; km < 24; ++km)
    s_barb[t][km] = s_sw[t] * (bb[km*64 + t] - s_bw[km]);
  __syncthreads();
  {
    int k = t >> 3, k2 = t & 7;
    float a = 0;
    for (int n = 0; n < 64; n++)
      for (int j = 0; j < 3; j++)
        a += s_barb[n][k*3 + j] * s_barb[n][k2*3 + j];
    s_BtB[t] = a;
  }
  __syncthreads();
  if (t == 0) {
    const float lv = lam[0];
    float A[8][8], Iv[8][8];
#pragma unroll
    for (int i = 0; i < 8; i++)
#pragma unroll
      for (int j = 0; j < 8; j++) {
        A[i][j]  = 2.0f * (s_BtB[i*8 + j] + ((i == j) ? lv : 0.0f));
        Iv[i][j] = (i == j) ? 1.0f : 0.0f;
      }
#pragma unroll
    for (int k = 0; k < 8; k++) {
      float piv = 1.0f / A[k][k];
#pragma unroll
      for (int j = 0; j < 8; j++) { A[k][j] *= piv; Iv[k][j] *= piv; }
#pragma unroll
      for (int i = 0; i < 8; i++) {
        if (i == k) continue;
        float f = A[i][k];
#pragma unroll
        for (int j = 0; j < 8; j++) { A[i][j] -= f * A[k][j]; Iv[i][j] -= f * Iv[k][j]; }
      }
    }
    float u[8]; float s = 0;
#pragma unroll
    for (int i = 0; i < 8; i++) {
      float a = 0;
#pragma unroll
      for (int j = 0; j < 8; j++) a += Iv[i][j];
      u[i] = a; s += a;
    }
#pragma unroll
    for (int i = 0; i < 8; i++) s_g[i] = u[i] / s;
    float q00 = 0.0f;
#pragma unroll
    for (int i = 0; i < 8; i++)
#pragma unroll
      for (int j = 0; j < 8; j++) {
        s_G[i*8 + j] = Iv[i][j] - u[i]*u[j]/s;
        q00 += s_g[i] * (s_BtB[i*8 + j] + ((i == j) ? lv : 0.0f)) * s_g[j];
      }
    ws[WS_Q00]  = q00;
    ws[WS_WSUM] = wsum;
  }
  __syncthreads();
  if (t < 8)  ws[WS_g + t]  = s_g[t];
  if (t < 24) ws[WS_BW + t] = s_bw[t];
  ws[WS_G + t] = s_G[t];
  {
    float* c = ws + WS_COEF + t*28;
    c[0] = s_w[t];
    float qc[3] = {0, 0, 0};
#pragma unroll
    for (int km = 0; km < 24; km++) {
      float cb = s_sw[t] * s_barb[t][km];
      c[4 + km] = cb;
      qc[km % 3] += s_g[km / 3] * cb;
    }
    c[1] = qc[0]; c[2] = qc[1]; c[3] = qc[2];
  }
}

// ---------------- K2: per-batch Q build ----------------
__global__ __launch_bounds__(256) void k_build(const float* __restrict__ y, float* ws)
{
  const int b = blockIdx.x * 256 + threadIdx.x;
  const float* yb = y + (size_t)b * 192;
  const float* coef = ws + WS_COEF;
  float F[24][3];
  float qt[3][3];
  float gw[6];
  float ywa[3] = {0, 0, 0};
#pragma unroll
  for (int i = 0; i < 24; i++) { F[i][0] = 0; F[i][1] = 0; F[i][2] = 0; }
#pragma unroll
  for (int i = 0; i < 9; i++) qt[i/3][i%3] = 0;
#pragma unroll
  for (int i = 0; i < 6; i++) gw[i] = 0;

  for (int n4 = 0; n4 < 16; n4++) {
    float4 v0 = reinterpret_cast<const float4*>(yb)[n4];
    float4 v1 = reinterpret_cast<const float4*>(yb + 64)[n4];
    float4 v2 = reinterpret_cast<const float4*>(yb + 128)[n4];
    float a0[4] = {v0.x, v0.y, v0.z, v0.w};
    float a1[4] = {v1.x, v1.y, v1.z, v1.w};
    float a2[4] = {v2.x, v2.y, v2.z, v2.w};
#pragma unroll
    for (int l = 0; l < 4; l++) {
      const int n = 4*n4 + l;
      const float* c = coef + n*28;
      float ym0 = a0[l], ym1 = a1[l], ym2 = a2[l];
      float wn  = c[0];
      float wy0 = wn*ym0, wy1 = wn*ym1, wy2 = wn*ym2;
      ywa[0] += wy0; ywa[1] += wy1; ywa[2] += wy2;
      gw[0] += wy0*ym0; gw[1] += wy0*ym1; gw[2] += wy0*ym2;
      gw[3] += wy1*ym1; gw[4] += wy1*ym2; gw[5] += wy2*ym2;
#pragma unroll
      for (int j = 0; j < 3; j++) {
        float qcv = c[1 + j];
        qt[j][0] += qcv*ym0; qt[j][1] += qcv*ym1; qt[j][2] += qcv*ym2;
      }
#pragma unroll
      for (int kj = 0; kj < 24; kj++) {
        float cb = c[4 + kj];
        F[kj][0] += cb*ym0; F[kj][1] += cb*ym1; F[kj][2] += cb*ym2;
      }
    }
  }
  const float wsum = ws[WS_WSUM];
  const float q00  = ws[WS_Q00];
  const float iws  = 1.0f / wsum;
  float yw[3] = {ywa[0]*iws, ywa[1]*iws, ywa[2]*iws};
  float Gram[3][3];
  Gram[0][0] = gw[0] - ywa[0]*ywa[0]*iws;
  Gram[0][1] = Gram[1][0] = gw[1] - ywa[0]*ywa[1]*iws;
  Gram[0][2] = Gram[2][0] = gw[2] - ywa[0]*ywa[2]*iws;
  Gram[1][1] = gw[3] - ywa[1]*ywa[1]*iws;
  Gram[1][2] = Gram[2][1] = gw[4] - ywa[1]*ywa[2]*iws;
  Gram[2][2] = gw[5] - ywa[2]*ywa[2]*iws;

  float Gm[64];
#pragma unroll
  for (int i = 0; i < 64; i++) Gm[i] = ws[WS_G + i];
  float FG[8][9];
#pragma unroll
  for (int k2 = 0; k2 < 8; k2++)
#pragma unroll
    for (int e = 0; e < 9; e++) {
      const int j = e / 3, m = e % 3;
      float a = 0;
#pragma unroll
      for (int k = 0; k < 8; k++) a += Gm[k*8 + k2] * F[k*3 + j][m];
      FG[k2][e] = a;
    }
  float q[55];
  q[tidx(0,0)] = q00;
#pragma unroll
  for (int e = 0; e < 9; e++) q[tidx(0, 1 + e)] = -qt[e/3][e%3];
#pragma unroll
  for (int e = 0; e < 9; e++)
#pragma unroll
    for (int f = e; f < 9; f++) {
      const int j = e/3, m = e%3, j2 = f/3, m2 = f%3;
      float a = 0;
#pragma unroll
      for (int k = 0; k < 8; k++) a += FG[k][e] * F[k*3 + j2][m2];
      q[tidx(1 + e, 1 + f)] = -2.0f*a + ((j == j2) ? Gram[m][m2] : 0.0f);
    }
  float* wb = ws + WS_BATCH;
#pragma unroll
  for (int i = 0; i < 55; i++) wb[(size_t)i*Bn + b] = q[i];
#pragma unroll
  for (int k = 0; k < 8; k++)
#pragma unroll
    for (int e = 0; e < 9; e++)
      wb[(size_t)(55 + k*9 + e)*Bn + b] = FG[k][e];
#pragma unroll
  for (int m = 0; m < 3; m++) wb[(size_t)(127 + m)*Bn + b] = yw[m];
}

// ---------------- K3a: eigenvalue-only cyclic Jacobi -> lmin (template-forced regs) ----------------
__global__ __launch_bounds__(64, 1) void k_jac(const float* __restrict__ ws,
                                               float* __restrict__ ws_out)
{
  const int b = blockIdx.x * 64 + threadIdx.x;
  const float* wb = ws + WS_BATCH;
  S10 A;
  loadA<0>(A, wb, b);

  for (int sweep = 0; sweep < NSWEEP; ++sweep)
    sweepFrom<0, 1>(A);

  float lmin = at<tidx(0,0)>(A);
  dmin<1>(A, lmin);
  ws_out[WS_LMIN + b] = lmin;
}

// ---------------- K3b: Cholesky inverse iteration + outputs ----------------
__global__ __launch_bounds__(64, 1) void k_vec(const float* __restrict__ ws,
                                               float* __restrict__ out)
{
  const int b = blockIdx.x * 64 + threadIdx.x;
  const float* wb = ws + WS_BATCH;
  const float lmin = ws[WS_LMIN + b];

  float M[55];                 // packed lower
  float id[10];
#pragma unroll
  for (int i = 0; i < 10; i++)
#pragma unroll
    for (int j = 0; j <= i; j++)
      M[lidx(i,j)] = wb[(size_t)tidx(j,i)*Bn + b];
  float tr = 0.0f;
#pragma unroll
  for (int i = 0; i < 10; i++) tr += M[lidx(i,i)];

  const float delta = 1e-5f * fabsf(tr) + 1e-30f;   // round-2 margin
  const float sigma = lmin - delta;
#pragma unroll
  for (int i = 0; i < 10; i++) M[lidx(i,i)] -= sigma;

#pragma unroll
  for (int j = 0; j < 10; j++) {
    float d = M[lidx(j,j)];
#pragma unroll
    for (int t2 = 0; t2 < j; t2++) d -= M[lidx(j,t2)] * M[lidx(j,t2)];
    d = fmaxf(d, 1e-30f);                            // round-2 floor
    float is = __builtin_amdgcn_rsqf(d);
    id[j] = is;
#pragma unroll
    for (int i = j + 1; i < 10; i++) {
      float a = M[lidx(i,j)];
#pragma unroll
      for (int t2 = 0; t2 < j; t2++) a -= M[lidx(i,t2)] * M[lidx(j,t2)];
      M[lidx(i,j)] = a * is;
    }
  }

  float x[10];
#pragma unroll
  for (int i = 0; i < 10; i++) x[i] = 1.0f;

#pragma unroll
  for (int it = 0; it < 3; ++it) {
#pragma unroll
    for (int i = 0; i < 10; i++) {
      float a = x[i];
#pragma unroll
      for (int j = 0; j < i; j++) a -= M[lidx(i,j)] * x[j];
      x[i] = a * id[i];
    }
#pragma unroll
    for (int i = 9; i >= 0; i--) {
      float a = x[i];
#pragma unroll
      for (int j = i + 1; j < 10; j++) a -= M[lidx(j,i)] * x[j];
      x[i] = a * id[i];
    }
    float s2 = 0;
#pragma unroll
    for (int i = 0; i < 10; i++) s2 += x[i]*x[i];
    float sc = __builtin_amdgcn_rsqf(s2 + 1e-38f);
#pragma unroll
    for (int i = 0; i < 10; i++) x[i] *= sc;
  }

  const float inv0 = __builtin_amdgcn_rcpf(x[0]);
  float R[3][3];
#pragma unroll
  for (int r = 0; r < 3; r++)
#pragma unroll
    for (int cc = 0; cc < 3; cc++)
      R[r][cc] = x[1 + 3*cc + r] * inv0;
  float cvec[8];
#pragma unroll
  for (int k = 0; k < 8; k++) {
    float a = 0;
#pragma unroll
    for (int e = 0; e < 9; e++) a += x[1 + e] * wb[(size_t)(55 + k*9 + e)*Bn + b];
    cvec[k] = 2.0f * inv0 * a + ws[WS_g + k];
  }
  float um[3] = {0, 0, 0};
#pragma unroll
  for (int k = 0; k < 8; k++) {
    float ck = cvec[k];
    um[0] += ws[WS_BW + k*3 + 0] * ck;
    um[1] += ws[WS_BW + k*3 + 1] * ck;
    um[2] += ws[WS_BW + k*3 + 2] * ck;
  }
#pragma unroll
  for (int r = 0; r < 3; r++)
#pragma unroll
    for (int cc = 0; cc < 3; cc++)
      out[(size_t)b*9 + r*3 + cc] = R[r][cc];
#pragma unroll
  for (int r = 0; r < 3; r++) {
    float yw = wb[(size_t)(127 + r)*Bn + b];
    out[(size_t)9*Bn + b*3 + r] = yw - (R[r][0]*um[0] + R[r][1]*um[1] + R[r][2]*um[2]);
  }
#pragma unroll
  for (int k = 0; k < 8; k++)
    out[(size_t)12*Bn + b*8 + k] = cvec[k];
}

extern "C" void kernel_launch(void* const* d_in, const int* in_sizes, int n_in,
                              void* d_out, int out_size, void* d_ws, size_t ws_size,
                              hipStream_t stream) {
  const float* y   = (const float*)d_in[0];
  const float* bb  = (const float*)d_in[1];
  const float* w   = (const float*)d_in[2];
  const float* lam = (const float*)d_in[3];
  float* ws  = (float*)d_ws;
  float* out = (float*)d_out;
  k_pre  <<<1,        64, 0, stream>>>(bb, w, lam, ws);
  k_build<<<Bn/256,  256, 0, stream>>>(y, ws);
  k_jac  <<<Bn/64,    64, 0, stream>>>(ws, ws);
  k_vec  <<<Bn/64,    64, 0, stream>>>(ws, out);
}

// Round 6
// 78.055 us; speedup vs baseline: 1.9081x; 1.1620x over previous
//
#include <hip/hip_runtime.h>
#include <math.h>

static constexpr int Bn = 32768;

// ws layout (floats)
#define WS_COEF  0        // [64][28] : per n {w, qc[3], cb[24]}  (cb idx = k*3+j)
#define WS_G     1792     // [8][8]
#define WS_g     1856     // [8]
#define WS_BW    1864     // [24]  b_w[k*3+m]
#define WS_Q00   1888
#define WS_WSUM  1889
#define WS_BATCH 1920     // [130][Bn] : 0..54 Qsym(upper), 55..126 FG[k*9+e], 127..129 y_w
#define WS_LMIN  (1920 + 130*Bn)   // [Bn]

__host__ __device__ constexpr int tidx(int i, int j) { return i*10 - i*(i+1)/2 + j; } // i<=j (upper packed)
__host__ __device__ constexpr int tmm(int i, int j)  { return (i<j) ? tidx(i,j) : tidx(j,i); }
__host__ __device__ constexpr int lidx(int i, int j) { return i*(i+1)/2 + j; }        // i>=j (lower packed)
__host__ __device__ constexpr int lodx(int i, int j) { return i*(i-1)/2 + j; }        // i>j (strict lower packed)

// ---------------- K1: precompute (1 block, 64 threads) ----------------
__global__ void k_pre(const float* __restrict__ bb, const float* __restrict__ w,
                      const float* __restrict__ lam, float* __restrict__ ws)
{
  __shared__ float s_w[64], s_sw[64], s_bw[24], s_barb[64][24];
  __shared__ float s_BtB[64];
  __shared__ float s_G[64], s_g[8], s_wsum;
  const int t = threadIdx.x;
  s_w[t]  = w[t];
  s_sw[t] = sqrtf(fmaxf(s_w[t], 0.0f));
  __syncthreads();
  if (t == 0) { float a = 0; for (int n = 0; n < 64; n++) a += s_w[n]; s_wsum = a; }
  __syncthreads();
  const float wsum = s_wsum;
  if (t < 24) {
    float a = 0;
    for (int n = 0; n < 64; n++) a += bb[t*64 + n] * s_w[n];
    s_bw[t] = a / wsum;
  }
  __syncthreads();
  for (int km = 0; km < 24; ++km)
    s_barb[t][km] = s_sw[t] * (bb[km*64 + t] - s_bw[km]);
  __syncthreads();
  {
    int k = t >> 3, k2 = t & 7;
    float a = 0;
    for (int n = 0; n < 64; n++)
      for (int j = 0; j < 3; j++)
        a += s_barb[n][k*3 + j] * s_barb[n][k2*3 + j];
    s_BtB[t] = a;
  }
  __syncthreads();
  if (t == 0) {
    const float lv = lam[0];
    float A[8][8], Iv[8][8];
#pragma unroll
    for (int i = 0; i < 8; i++)
#pragma unroll
      for (int j = 0; j < 8; j++) {
        A[i][j]  = 2.0f * (s_BtB[i*8 + j] + ((i == j) ? lv : 0.0f));
        Iv[i][j] = (i == j) ? 1.0f : 0.0f;
      }
#pragma unroll
    for (int k = 0; k < 8; k++) {
      float piv = 1.0f / A[k][k];
#pragma unroll
      for (int j = 0; j < 8; j++) { A[k][j] *= piv; Iv[k][j] *= piv; }
#pragma unroll
      for (int i = 0; i < 8; i++) {
        if (i == k) continue;
        float f = A[i][k];
#pragma unroll
        for (int j = 0; j < 8; j++) { A[i][j] -= f * A[k][j]; Iv[i][j] -= f * Iv[k][j]; }
      }
    }
    float u[8]; float s = 0;
#pragma unroll
    for (int i = 0; i < 8; i++) {
      float a = 0;
#pragma unroll
      for (int j = 0; j < 8; j++) a += Iv[i][j];
      u[i] = a; s += a;
    }
#pragma unroll
    for (int i = 0; i < 8; i++) s_g[i] = u[i] / s;
    float q00 = 0.0f;
#pragma unroll
    for (int i = 0; i < 8; i++)
#pragma unroll
      for (int j = 0; j < 8; j++) {
        s_G[i*8 + j] = Iv[i][j] - u[i]*u[j]/s;
        q00 += s_g[i] * (s_BtB[i*8 + j] + ((i == j) ? lv : 0.0f)) * s_g[j];
      }
    ws[WS_Q00]  = q00;
    ws[WS_WSUM] = wsum;
  }
  __syncthreads();
  if (t < 8)  ws[WS_g + t]  = s_g[t];
  if (t < 24) ws[WS_BW + t] = s_bw[t];
  ws[WS_G + t] = s_G[t];
  {
    float* c = ws + WS_COEF + t*28;
    c[0] = s_w[t];
    float qc[3] = {0, 0, 0};
#pragma unroll
    for (int km = 0; km < 24; km++) {
      float cb = s_sw[t] * s_barb[t][km];
      c[4 + km] = cb;
      qc[km % 3] += s_g[km / 3] * cb;
    }
    c[1] = qc[0]; c[2] = qc[1]; c[3] = qc[2];
  }
}

// ---------------- K2: per-batch Q build ----------------
__global__ __launch_bounds__(256) void k_build(const float* __restrict__ y, float* ws)
{
  const int b = blockIdx.x * 256 + threadIdx.x;
  const float* yb = y + (size_t)b * 192;
  const float* coef = ws + WS_COEF;
  float F[24][3];
  float qt[3][3];
  float gw[6];
  float ywa[3] = {0, 0, 0};
#pragma unroll
  for (int i = 0; i < 24; i++) { F[i][0] = 0; F[i][1] = 0; F[i][2] = 0; }
#pragma unroll
  for (int i = 0; i < 9; i++) qt[i/3][i%3] = 0;
#pragma unroll
  for (int i = 0; i < 6; i++) gw[i] = 0;

  for (int n4 = 0; n4 < 16; n4++) {
    float4 v0 = reinterpret_cast<const float4*>(yb)[n4];
    float4 v1 = reinterpret_cast<const float4*>(yb + 64)[n4];
    float4 v2 = reinterpret_cast<const float4*>(yb + 128)[n4];
    float a0[4] = {v0.x, v0.y, v0.z, v0.w};
    float a1[4] = {v1.x, v1.y, v1.z, v1.w};
    float a2[4] = {v2.x, v2.y, v2.z, v2.w};
#pragma unroll
    for (int l = 0; l < 4; l++) {
      const int n = 4*n4 + l;
      const float* c = coef + n*28;
      float ym0 = a0[l], ym1 = a1[l], ym2 = a2[l];
      float wn  = c[0];
      float wy0 = wn*ym0, wy1 = wn*ym1, wy2 = wn*ym2;
      ywa[0] += wy0; ywa[1] += wy1; ywa[2] += wy2;
      gw[0] += wy0*ym0; gw[1] += wy0*ym1; gw[2] += wy0*ym2;
      gw[3] += wy1*ym1; gw[4] += wy1*ym2; gw[5] += wy2*ym2;
#pragma unroll
      for (int j = 0; j < 3; j++) {
        float qcv = c[1 + j];
        qt[j][0] += qcv*ym0; qt[j][1] += qcv*ym1; qt[j][2] += qcv*ym2;
      }
#pragma unroll
      for (int kj = 0; kj < 24; kj++) {
        float cb = c[4 + kj];
        F[kj][0] += cb*ym0; F[kj][1] += cb*ym1; F[kj][2] += cb*ym2;
      }
    }
  }
  const float wsum = ws[WS_WSUM];
  const float q00  = ws[WS_Q00];
  const float iws  = 1.0f / wsum;
  float yw[3] = {ywa[0]*iws, ywa[1]*iws, ywa[2]*iws};
  float Gram[3][3];
  Gram[0][0] = gw[0] - ywa[0]*ywa[0]*iws;
  Gram[0][1] = Gram[1][0] = gw[1] - ywa[0]*ywa[1]*iws;
  Gram[0][2] = Gram[2][0] = gw[2] - ywa[0]*ywa[2]*iws;
  Gram[1][1] = gw[3] - ywa[1]*ywa[1]*iws;
  Gram[1][2] = Gram[2][1] = gw[4] - ywa[1]*ywa[2]*iws;
  Gram[2][2] = gw[5] - ywa[2]*ywa[2]*iws;

  float Gm[64];
#pragma unroll
  for (int i = 0; i < 64; i++) Gm[i] = ws[WS_G + i];
  float FG[8][9];
#pragma unroll
  for (int k2 = 0; k2 < 8; k2++)
#pragma unroll
    for (int e = 0; e < 9; e++) {
      const int j = e / 3, m = e % 3;
      float a = 0;
#pragma unroll
      for (int k = 0; k < 8; k++) a += Gm[k*8 + k2] * F[k*3 + j][m];
      FG[k2][e] = a;
    }
  float q[55];
  q[tidx(0,0)] = q00;
#pragma unroll
  for (int e = 0; e < 9; e++) q[tidx(0, 1 + e)] = -qt[e/3][e%3];
#pragma unroll
  for (int e = 0; e < 9; e++)
#pragma unroll
    for (int f = e; f < 9; f++) {
      const int j = e/3, m = e%3, j2 = f/3, m2 = f%3;
      float a = 0;
#pragma unroll
      for (int k = 0; k < 8; k++) a += FG[k][e] * F[k*3 + j2][m2];
      q[tidx(1 + e, 1 + f)] = -2.0f*a + ((j == j2) ? Gram[m][m2] : 0.0f);
    }
  float* wb = ws + WS_BATCH;
#pragma unroll
  for (int i = 0; i < 55; i++) wb[(size_t)i*Bn + b] = q[i];
#pragma unroll
  for (int k = 0; k < 8; k++)
#pragma unroll
    for (int e = 0; e < 9; e++)
      wb[(size_t)(55 + k*9 + e)*Bn + b] = FG[k][e];
#pragma unroll
  for (int m = 0; m < 3; m++) wb[(size_t)(127 + m)*Bn + b] = yw[m];
}

// ---------------- K3a: lmin via Sturm bisection (LDLT inertia count) ----------------
__global__ __launch_bounds__(64, 1) void k_jac(const float* __restrict__ ws,
                                               float* __restrict__ ws_out)
{
  const int b = blockIdx.x * 64 + threadIdx.x;
  const float* wb = ws + WS_BATCH;
  float A[55];
#pragma unroll
  for (int i = 0; i < 55; i++) A[i] = wb[(size_t)i*Bn + b];

  // bracket: Q is PSD (Gram-structured) => lambda_min >= -eps; interlacing => lambda_min <= min diag
  float hi = A[tidx(0,0)];
#pragma unroll
  for (int j = 1; j < 10; j++) hi = fminf(hi, A[tidx(j,j)]);
  float lo = 0.0f;

  for (int it = 0; it < 22; ++it) {
    const float mid = 0.5f * (lo + hi);
    float L[45];       // strict lower, packed lodx
    float d[10];
    int neg = 0;
#pragma unroll
    for (int j = 0; j < 10; j++) {
      float dj = A[tidx(j,j)] - mid;
#pragma unroll
      for (int k = 0; k < j; k++) dj -= L[lodx(j,k)] * L[lodx(j,k)] * d[k];
      dj = (fabsf(dj) < 1e-30f) ? -1e-30f : dj;   // zero-pivot guard (errs toward sigma below lmin)
      d[j] = dj;
      neg += (dj < 0.0f) ? 1 : 0;
      float inv = __builtin_amdgcn_rcpf(dj);
#pragma unroll
      for (int i2 = j + 1; i2 < 10; i2++) {
        float s = A[tmm(i2,j)];
#pragma unroll
        for (int k = 0; k < j; k++) s -= L[lodx(i2,k)] * L[lodx(j,k)] * d[k];
        L[lodx(i2,j)] = s * inv;
      }
    }
    if (neg == 0) lo = mid; else hi = mid;
  }
  // lo <= lambda_min, lambda_min - lo <= 2^-22 * hi0  (<< the 1e-5*tr shift pad in k_vec)
  ws_out[WS_LMIN + b] = lo;
}

// ---------------- K3b: Cholesky inverse iteration + outputs ----------------
__global__ __launch_bounds__(64, 1) void k_vec(const float* __restrict__ ws,
                                               float* __restrict__ out)
{
  const int b = blockIdx.x * 64 + threadIdx.x;
  const float* wb = ws + WS_BATCH;
  const float lmin = ws[WS_LMIN + b];

  float M[55];                 // packed lower
  float id[10];
#pragma unroll
  for (int i = 0; i < 10; i++)
#pragma unroll
    for (int j = 0; j <= i; j++)
      M[lidx(i,j)] = wb[(size_t)tidx(j,i)*Bn + b];
  float tr = 0.0f;
#pragma unroll
  for (int i = 0; i < 10; i++) tr += M[lidx(i,i)];

  const float delta = 1e-5f * fabsf(tr) + 1e-30f;   // round-2 margin
  const float sigma = lmin - delta;
#pragma unroll
  for (int i = 0; i < 10; i++) M[lidx(i,i)] -= sigma;

#pragma unroll
  for (int j = 0; j < 10; j++) {
    float d = M[lidx(j,j)];
#pragma unroll
    for (int t2 = 0; t2 < j; t2++) d -= M[lidx(j,t2)] * M[lidx(j,t2)];
    d = fmaxf(d, 1e-30f);                            // round-2 floor
    float is = __builtin_amdgcn_rsqf(d);
    id[j] = is;
#pragma unroll
    for (int i = j + 1; i < 10; i++) {
      float a = M[lidx(i,j)];
#pragma unroll
      for (int t2 = 0; t2 < j; t2++) a -= M[lidx(i,t2)] * M[lidx(j,t2)];
      M[lidx(i,j)] = a * is;
    }
  }

  float x[10];
#pragma unroll
  for (int i = 0; i < 10; i++) x[i] = 1.0f;

#pragma unroll
  for (int it = 0; it < 3; ++it) {
#pragma unroll
    for (int i = 0; i < 10; i++) {
      float a = x[i];
#pragma unroll
      for (int j = 0; j < i; j++) a -= M[lidx(i,j)] * x[j];
      x[i] = a * id[i];
    }
#pragma unroll
    for (int i = 9; i >= 0; i--) {
      float a = x[i];
#pragma unroll
      for (int j = i + 1; j < 10; j++) a -= M[lidx(j,i)] * x[j];
      x[i] = a * id[i];
    }
    float s2 = 0;
#pragma unroll
    for (int i = 0; i < 10; i++) s2 += x[i]*x[i];
    float sc = __builtin_amdgcn_rsqf(s2 + 1e-38f);
#pragma unroll
    for (int i = 0; i < 10; i++) x[i] *= sc;
  }

  const float inv0 = __builtin_amdgcn_rcpf(x[0]);
  float R[3][3];
#pragma unroll
  for (int r = 0; r < 3; r++)
#pragma unroll
    for (int cc = 0; cc < 3; cc++)
      R[r][cc] = x[1 + 3*cc + r] * inv0;
  float cvec[8];
#pragma unroll
  for (int k = 0; k < 8; k++) {
    float a = 0;
#pragma unroll
    for (int e = 0; e < 9; e++) a += x[1 + e] * wb[(size_t)(55 + k*9 + e)*Bn + b];
    cvec[k] = 2.0f * inv0 * a + ws[WS_g + k];
  }
  float um[3] = {0, 0, 0};
#pragma unroll
  for (int k = 0; k < 8; k++) {
    float ck = cvec[k];
    um[0] += ws[WS_BW + k*3 + 0] * ck;
    um[1] += ws[WS_BW + k*3 + 1] * ck;
    um[2] += ws[WS_BW + k*3 + 2] * ck;
  }
#pragma unroll
  for (int r = 0; r < 3; r++)
#pragma unroll
    for (int cc = 0; cc < 3; cc++)
      out[(size_t)b*9 + r*3 + cc] = R[r][cc];
#pragma unroll
  for (int r = 0; r < 3; r++) {
    float yw = wb[(size_t)(127 + r)*Bn + b];
    out[(size_t)9*Bn + b*3 + r] = yw - (R[r][0]*um[0] + R[r][1]*um[1] + R[r][2]*um[2]);
  }
#pragma unroll
  for (int k = 0; k < 8; k++)
    out[(size_t)12*Bn + b*8 + k] = cvec[k];
}

extern "C" void kernel_launch(void* const* d_in, const int* in_sizes, int n_in,
                              void* d_out, int out_size, void* d_ws, size_t ws_size,
                              hipStream_t stream) {
  const float* y   = (const float*)d_in[0];
  const float* bb  = (const float*)d_in[1];
  const float* w   = (const float*)d_in[2];
  const float* lam = (const float*)d_in[3];
  float* ws  = (float*)d_ws;
  float* out = (float*)d_out;
  k_pre  <<<1,        64, 0, stream>>>(bb, w, lam, ws);
  k_build<<<Bn/256,  256, 0, stream>>>(y, ws);
  k_jac  <<<Bn/64,    64, 0, stream>>>(ws, ws);
  k_vec  <<<Bn/64,    64, 0, stream>>>(ws, out);
}

// Round 7
// 66.757 us; speedup vs baseline: 2.2310x; 1.1692x over previous
//
#include <hip/hip_runtime.h>
#include <math.h>

static constexpr int Bn = 32768;

// ws layout (floats)
#define WS_COEF  0        // [64][28] : per n {w, qc[3], cb[24]}  (cb idx = k*3+j)
#define WS_G     1792     // [8][8]
#define WS_g     1856     // [8]
#define WS_BW    1864     // [24]  b_w[k*3+m]
#define WS_Q00   1888
#define WS_WSUM  1889
#define WS_BATCH 1920     // [130][Bn] : 0..54 Qsym(upper), 55..126 FG[k*9+e], 127..129 y_w
#define WS_LMIN  (1920 + 130*Bn)   // [Bn]

__host__ __device__ constexpr int tidx(int i, int j) { return i*10 - i*(i+1)/2 + j; } // i<=j (upper packed)
__host__ __device__ constexpr int tmm(int i, int j)  { return (i<j) ? tidx(i,j) : tidx(j,i); }
__host__ __device__ constexpr int lidx(int i, int j) { return i*(i+1)/2 + j; }        // i>=j (lower packed)
__host__ __device__ constexpr int lodx(int i, int j) { return i*(i-1)/2 + j; }        // i>j (strict lower packed)

// ---------------- K1: precompute (1 block, 64 threads; GJ parallelized in LDS) ----------------
__global__ void k_pre(const float* __restrict__ bb, const float* __restrict__ w,
                      const float* __restrict__ lam, float* __restrict__ ws)
{
  __shared__ float s_w[64], s_sw[64], s_bw[24], s_barb[64][24];
  __shared__ float s_BtB[64];
  __shared__ float s_M[8][16];      // [A | Iv]
  __shared__ float s_u[8], s_g[8], s_red[64], s_wsum, s_s;
  const int t = threadIdx.x;
  const int i8 = t >> 3, j8 = t & 7;
  const float lv = lam[0];

  s_w[t]  = w[t];
  s_sw[t] = sqrtf(fmaxf(s_w[t], 0.0f));
  __syncthreads();
  if (t == 0) { float a = 0; for (int n = 0; n < 64; n++) a += s_w[n]; s_wsum = a; }
  __syncthreads();
  const float wsum = s_wsum;
  if (t < 24) {                       // b_w[k*3+m]
    float a = 0;
    for (int n = 0; n < 64; n++) a += bb[t*64 + n] * s_w[n];
    s_bw[t] = a / wsum;
  }
  __syncthreads();
  for (int km = 0; km < 24; ++km)     // bar_b[n][km], t = n
    s_barb[t][km] = s_sw[t] * (bb[km*64 + t] - s_bw[km]);
  __syncthreads();
  {                                    // BtB, t = k*8+k2
    float a = 0;
    for (int n = 0; n < 64; n++)
      for (int j = 0; j < 3; j++)
        a += s_barb[n][i8*3 + j] * s_barb[n][j8*3 + j];
    s_BtB[t] = a;
  }
  __syncthreads();
  // ---- parallel Gauss-Jordan on [A | I], thread t owns (i8, j8) and (i8, 8+j8) ----
  s_M[i8][j8]     = 2.0f * (s_BtB[t] + ((i8 == j8) ? lv : 0.0f));
  s_M[i8][8 + j8] = (i8 == j8) ? 1.0f : 0.0f;
#pragma unroll
  for (int k = 0; k < 8; k++) {
    __syncthreads();
    const float fk  = s_M[i8][k];                       // my row's col-k entry (pre-scale)
    const float piv = 1.0f / s_M[k][k];
    __syncthreads();
    if (i8 == k) { s_M[k][j8] *= piv; s_M[k][8 + j8] *= piv; }
    __syncthreads();
    if (i8 != k) {
      s_M[i8][j8]     -= fk * s_M[k][j8];
      s_M[i8][8 + j8] -= fk * s_M[k][8 + j8];
    }
  }
  __syncthreads();
  if (t < 8) {                         // u[i] = row-sum of inverse
    float a = 0;
#pragma unroll
    for (int j = 0; j < 8; j++) a += s_M[t][8 + j];
    s_u[t] = a;
  }
  __syncthreads();
  if (t == 0) {
    float s = 0;
#pragma unroll
    for (int j = 0; j < 8; j++) s += s_u[j];
    s_s = s;
  }
  __syncthreads();
  const float s = s_s;
  if (t < 8) s_g[t] = s_u[t] / s;
  // G[i][j] = Hinv[i][j] - u_i u_j / s  (one element per thread)
  const float Gel = s_M[i8][8 + j8] - s_u[i8] * s_u[j8] / s;
  ws[WS_G + t] = Gel;
  __syncthreads();
  // q00 = g^T (BtB + lam I) g  — per-thread term, reduce
  s_red[t] = s_g[i8] * (s_BtB[t] + ((i8 == j8) ? lv : 0.0f)) * s_g[j8];
  __syncthreads();
  if (t == 0) {
    float a = 0;
    for (int n = 0; n < 64; n++) a += s_red[n];
    ws[WS_Q00]  = a;
    ws[WS_WSUM] = wsum;
  }
  if (t < 8)  ws[WS_g + t]  = s_g[t];
  if (t < 24) ws[WS_BW + t] = s_bw[t];
  {                                     // packed per-n coefficients, t = n
    float* c = ws + WS_COEF + t*28;
    c[0] = s_w[t];
    float qc[3] = {0, 0, 0};
#pragma unroll
    for (int km = 0; km < 24; km++) {
      float cb = s_sw[t] * s_barb[t][km];
      c[4 + km] = cb;
      qc[km % 3] += s_g[km / 3] * cb;
    }
    c[1] = qc[0]; c[2] = qc[1]; c[3] = qc[2];
  }
}

// ---------------- K2: per-batch Q build ----------------
__global__ __launch_bounds__(256) void k_build(const float* __restrict__ y, float* ws)
{
  const int b = blockIdx.x * 256 + threadIdx.x;
  const float* yb = y + (size_t)b * 192;
  const float* coef = ws + WS_COEF;
  float F[24][3];
  float qt[3][3];
  float gw[6];
  float ywa[3] = {0, 0, 0};
#pragma unroll
  for (int i = 0; i < 24; i++) { F[i][0] = 0; F[i][1] = 0; F[i][2] = 0; }
#pragma unroll
  for (int i = 0; i < 9; i++) qt[i/3][i%3] = 0;
#pragma unroll
  for (int i = 0; i < 6; i++) gw[i] = 0;

  for (int n4 = 0; n4 < 16; n4++) {
    float4 v0 = reinterpret_cast<const float4*>(yb)[n4];
    float4 v1 = reinterpret_cast<const float4*>(yb + 64)[n4];
    float4 v2 = reinterpret_cast<const float4*>(yb + 128)[n4];
    float a0[4] = {v0.x, v0.y, v0.z, v0.w};
    float a1[4] = {v1.x, v1.y, v1.z, v1.w};
    float a2[4] = {v2.x, v2.y, v2.z, v2.w};
#pragma unroll
    for (int l = 0; l < 4; l++) {
      const int n = 4*n4 + l;
      const float* c = coef + n*28;
      float ym0 = a0[l], ym1 = a1[l], ym2 = a2[l];
      float wn  = c[0];
      float wy0 = wn*ym0, wy1 = wn*ym1, wy2 = wn*ym2;
      ywa[0] += wy0; ywa[1] += wy1; ywa[2] += wy2;
      gw[0] += wy0*ym0; gw[1] += wy0*ym1; gw[2] += wy0*ym2;
      gw[3] += wy1*ym1; gw[4] += wy1*ym2; gw[5] += wy2*ym2;
#pragma unroll
      for (int j = 0; j < 3; j++) {
        float qcv = c[1 + j];
        qt[j][0] += qcv*ym0; qt[j][1] += qcv*ym1; qt[j][2] += qcv*ym2;
      }
#pragma unroll
      for (int kj = 0; kj < 24; kj++) {
        float cb = c[4 + kj];
        F[kj][0] += cb*ym0; F[kj][1] += cb*ym1; F[kj][2] += cb*ym2;
      }
    }
  }
  const float wsum = ws[WS_WSUM];
  const float q00  = ws[WS_Q00];
  const float iws  = 1.0f / wsum;
  float yw[3] = {ywa[0]*iws, ywa[1]*iws, ywa[2]*iws};
  float Gram[3][3];
  Gram[0][0] = gw[0] - ywa[0]*ywa[0]*iws;
  Gram[0][1] = Gram[1][0] = gw[1] - ywa[0]*ywa[1]*iws;
  Gram[0][2] = Gram[2][0] = gw[2] - ywa[0]*ywa[2]*iws;
  Gram[1][1] = gw[3] - ywa[1]*ywa[1]*iws;
  Gram[1][2] = Gram[2][1] = gw[4] - ywa[1]*ywa[2]*iws;
  Gram[2][2] = gw[5] - ywa[2]*ywa[2]*iws;

  float Gm[64];
#pragma unroll
  for (int i = 0; i < 64; i++) Gm[i] = ws[WS_G + i];
  float FG[8][9];
#pragma unroll
  for (int k2 = 0; k2 < 8; k2++)
#pragma unroll
    for (int e = 0; e < 9; e++) {
      const int j = e / 3, m = e % 3;
      float a = 0;
#pragma unroll
      for (int k = 0; k < 8; k++) a += Gm[k*8 + k2] * F[k*3 + j][m];
      FG[k2][e] = a;
    }
  float q[55];
  q[tidx(0,0)] = q00;
#pragma unroll
  for (int e = 0; e < 9; e++) q[tidx(0, 1 + e)] = -qt[e/3][e%3];
#pragma unroll
  for (int e = 0; e < 9; e++)
#pragma unroll
    for (int f = e; f < 9; f++) {
      const int j = e/3, m = e%3, j2 = f/3, m2 = f%3;
      float a = 0;
#pragma unroll
      for (int k = 0; k < 8; k++) a += FG[k][e] * F[k*3 + j2][m2];
      q[tidx(1 + e, 1 + f)] = -2.0f*a + ((j == j2) ? Gram[m][m2] : 0.0f);
    }
  float* wb = ws + WS_BATCH;
#pragma unroll
  for (int i = 0; i < 55; i++) wb[(size_t)i*Bn + b] = q[i];
#pragma unroll
  for (int k = 0; k < 8; k++)
#pragma unroll
    for (int e = 0; e < 9; e++)
      wb[(size_t)(55 + k*9 + e)*Bn + b] = FG[k][e];
#pragma unroll
  for (int m = 0; m < 3; m++) wb[(size_t)(127 + m)*Bn + b] = yw[m];
}

// ---------------- K3a: lmin via Sturm bisection (LDLT inertia count) ----------------
__global__ __launch_bounds__(64, 1) void k_jac(const float* __restrict__ ws,
                                               float* __restrict__ ws_out)
{
  const int b = blockIdx.x * 64 + threadIdx.x;
  const float* wb = ws + WS_BATCH;
  float A[55];
#pragma unroll
  for (int i = 0; i < 55; i++) A[i] = wb[(size_t)i*Bn + b];

  float hi = A[tidx(0,0)];
#pragma unroll
  for (int j = 1; j < 10; j++) hi = fminf(hi, A[tidx(j,j)]);
  float lo = 0.0f;

  for (int it = 0; it < 22; ++it) {
    const float mid = 0.5f * (lo + hi);
    float L[45];
    float d[10];
    int neg = 0;
#pragma unroll
    for (int j = 0; j < 10; j++) {
      float dj = A[tidx(j,j)] - mid;
#pragma unroll
      for (int k = 0; k < j; k++) dj -= L[lodx(j,k)] * L[lodx(j,k)] * d[k];
      dj = (fabsf(dj) < 1e-30f) ? -1e-30f : dj;
      d[j] = dj;
      neg += (dj < 0.0f) ? 1 : 0;
      float inv = __builtin_amdgcn_rcpf(dj);
#pragma unroll
      for (int i2 = j + 1; i2 < 10; i2++) {
        float s = A[tmm(i2,j)];
#pragma unroll
        for (int k = 0; k < j; k++) s -= L[lodx(i2,k)] * L[lodx(j,k)] * d[k];
        L[lodx(i2,j)] = s * inv;
      }
    }
    if (neg == 0) lo = mid; else hi = mid;
  }
  ws_out[WS_LMIN + b] = lo;
}

// ---------------- K3b: Cholesky inverse iteration + outputs ----------------
__global__ __launch_bounds__(64, 1) void k_vec(const float* __restrict__ ws,
                                               float* __restrict__ out)
{
  const int b = blockIdx.x * 64 + threadIdx.x;
  const float* wb = ws + WS_BATCH;
  const float lmin = ws[WS_LMIN + b];

  float M[55];
  float id[10];
#pragma unroll
  for (int i = 0; i < 10; i++)
#pragma unroll
    for (int j = 0; j <= i; j++)
      M[lidx(i,j)] = wb[(size_t)tidx(j,i)*Bn + b];
  float tr = 0.0f;
#pragma unroll
  for (int i = 0; i < 10; i++) tr += M[lidx(i,i)];

  const float delta = 1e-5f * fabsf(tr) + 1e-30f;
  const float sigma = lmin - delta;
#pragma unroll
  for (int i = 0; i < 10; i++) M[lidx(i,i)] -= sigma;

#pragma unroll
  for (int j = 0; j < 10; j++) {
    float d = M[lidx(j,j)];
#pragma unroll
    for (int t2 = 0; t2 < j; t2++) d -= M[lidx(j,t2)] * M[lidx(j,t2)];
    d = fmaxf(d, 1e-30f);
    float is = __builtin_amdgcn_rsqf(d);
    id[j] = is;
#pragma unroll
    for (int i = j + 1; i < 10; i++) {
      float a = M[lidx(i,j)];
#pragma unroll
      for (int t2 = 0; t2 < j; t2++) a -= M[lidx(i,t2)] * M[lidx(j,t2)];
      M[lidx(i,j)] = a * is;
    }
  }

  float x[10];
#pragma unroll
  for (int i = 0; i < 10; i++) x[i] = 1.0f;

#pragma unroll
  for (int it = 0; it < 3; ++it) {
#pragma unroll
    for (int i = 0; i < 10; i++) {
      float a = x[i];
#pragma unroll
      for (int j = 0; j < i; j++) a -= M[lidx(i,j)] * x[j];
      x[i] = a * id[i];
    }
#pragma unroll
    for (int i = 9; i >= 0; i--) {
      float a = x[i];
#pragma unroll
      for (int j = i + 1; j < 10; j++) a -= M[lidx(j,i)] * x[j];
      x[i] = a * id[i];
    }
    float s2 = 0;
#pragma unroll
    for (int i = 0; i < 10; i++) s2 += x[i]*x[i];
    float sc = __builtin_amdgcn_rsqf(s2 + 1e-38f);
#pragma unroll
    for (int i = 0; i < 10; i++) x[i] *= sc;
  }

  const float inv0 = __builtin_amdgcn_rcpf(x[0]);
  float R[3][3];
#pragma unroll
  for (int r = 0; r < 3; r++)
#pragma unroll
    for (int cc = 0; cc < 3; cc++)
      R[r][cc] = x[1 + 3*cc + r] * inv0;
  float cvec[8];
#pragma unroll
  for (int k = 0; k < 8; k++) {
    float a = 0;
#pragma unroll
    for (int e = 0; e < 9; e++) a += x[1 + e] * wb[(size_t)(55 + k*9 + e)*Bn + b];
    cvec[k] = 2.0f * inv0 * a + ws[WS_g + k];
  }
  float um[3] = {0, 0, 0};
#pragma unroll
  for (int k = 0; k < 8; k++) {
    float ck = cvec[k];
    um[0] += ws[WS_BW + k*3 + 0] * ck;
    um[1] += ws[WS_BW + k*3 + 1] * ck;
    um[2] += ws[WS_BW + k*3 + 2] * ck;
  }
#pragma unroll
  for (int r = 0; r < 3; r++)
#pragma unroll
    for (int cc = 0; cc < 3; cc++)
      out[(size_t)b*9 + r*3 + cc] = R[r][cc];
#pragma unroll
  for (int r = 0; r < 3; r++) {
    float yw = wb[(size_t)(127 + r)*Bn + b];
    out[(size_t)9*Bn + b*3 + r] = yw - (R[r][0]*um[0] + R[r][1]*um[1] + R[r][2]*um[2]);
  }
#pragma unroll
  for (int k = 0; k < 8; k++)
    out[(size_t)12*Bn + b*8 + k] = cvec[k];
}

extern "C" void kernel_launch(void* const* d_in, const int* in_sizes, int n_in,
                              void* d_out, int out_size, void* d_ws, size_t ws_size,
                              hipStream_t stream) {
  const float* y   = (const float*)d_in[0];
  const float* bb  = (const float*)d_in[1];
  const float* w   = (const float*)d_in[2];
  const float* lam = (const float*)d_in[3];
  float* ws  = (float*)d_ws;
  float* out = (float*)d_out;
  k_pre  <<<1,        64, 0, stream>>>(bb, w, lam, ws);
  k_build<<<Bn/256,  256, 0, stream>>>(y, ws);
  k_jac  <<<Bn/64,    64, 0, stream>>>(ws, ws);
  k_vec  <<<Bn/64,    64, 0, stream>>>(ws, out);
}